// Round 5
// baseline (197.610 us; speedup 1.0000x reference)
//
#include <hip/hip_runtime.h>
#include <stdint.h>

#define T_ 2048
#define BB_ 4

typedef __bf16 bf16x8 __attribute__((ext_vector_type(8)));
typedef float f32x4 __attribute__((ext_vector_type(4)));
typedef unsigned short u16x8 __attribute__((ext_vector_type(8)));
typedef unsigned int u32x2 __attribute__((ext_vector_type(2)));
typedef unsigned int u32x4 __attribute__((ext_vector_type(4)));

__device__ __forceinline__ unsigned short f2b(float f) {
    unsigned int u = __builtin_bit_cast(unsigned int, f);
    return (unsigned short)((u + 0x7fffu + ((u >> 16) & 1u)) >> 16);
}

__device__ __forceinline__ unsigned cvt_pk(float lo, float hi) {
    unsigned r;
    asm("v_cvt_pk_bf16_f32 %0, %1, %2" : "=v"(r) : "v"(lo), "v"(hi));
    return r;
}

__device__ __forceinline__ void gload16(const void* g, const void* lds) {
    __builtin_amdgcn_global_load_lds(
        (__attribute__((address_space(1))) void*)(uintptr_t)g,
        (__attribute__((address_space(3))) void*)(uintptr_t)(unsigned int)(uintptr_t)lds,
        16, 0, 0);
}

__device__ __forceinline__ bf16x8 ld_b8(const unsigned short* p) {
    return *(const bf16x8*)p;
}

#define MFMA16(a, b, c) __builtin_amdgcn_mfma_f32_16x16x32_bf16((a), (b), (c), 0, 0, 0)

// ---------------- fp32 -> bf16 elementwise ----------------
__global__ __launch_bounds__(256) void k_cvt(const float* __restrict__ in,
                                             unsigned short* __restrict__ out, int n) {
    int i = (blockIdx.x * 256 + threadIdx.x) * 4;
    const int stride = gridDim.x * 256 * 4;
    for (; i < n; i += stride) {
        const float4 v = *(const float4*)(in + i);
        ushort4 o = make_ushort4(f2b(v.x), f2b(v.y), f2b(v.z), f2b(v.w));
        *(ushort4*)(out + i) = o;
    }
}

// ---------------- fp32 (K x N) -> bf16 transposed (N x K) ----------------
template <int K, int N>
__global__ __launch_bounds__(256) void k_cvt_T(const float* __restrict__ W,
                                               unsigned short* __restrict__ WT) {
    __shared__ unsigned short t_[64][72];
    const int nt = blockIdx.x % (N / 64), kt = blockIdx.x / (N / 64);
    const int tid = threadIdx.x;
    const int r = tid >> 2, c = (tid & 3) * 16;
    const float* src = W + (size_t)(kt * 64 + r) * N + nt * 64 + c;
#pragma unroll
    for (int j = 0; j < 16; j += 4) {
        float4 v = *(const float4*)(src + j);
        t_[r][c + j + 0] = f2b(v.x);
        t_[r][c + j + 1] = f2b(v.y);
        t_[r][c + j + 2] = f2b(v.z);
        t_[r][c + j + 3] = f2b(v.w);
    }
    __syncthreads();
    unsigned short* dst = WT + (size_t)(nt * 64 + r) * K + kt * 64 + c;
#pragma unroll
    for (int j = 0; j < 16; ++j) dst[j] = t_[c + j][r];
}

// ---------------- bf16 GEMM: C[M][N] = A[M][K] * Bt[N][K]^T ----------------
template <int K, int OUTF>
__global__ __launch_bounds__(256) void k_gemm(const unsigned short* __restrict__ A,
                                              const unsigned short* __restrict__ Bt,
                                              void* __restrict__ Cv, int N) {
    __shared__ unsigned short As[128 * 32];
    __shared__ unsigned short Bs[128 * 32];
    const int tid = threadIdx.x;
    const int lane = tid & 63;
    const int wid = tid >> 6;
    const int wr = wid >> 1, wc = wid & 1;
    const int m0 = blockIdx.y * 128, n0 = blockIdx.x * 128;
    const int arow = lane >> 2;
    const int acol = (lane & 3) * 8;
    f32x4 acc[4][4] = {};

    const unsigned short* Abase = A + (size_t)(m0 + wid * 32 + arow) * K + acol;
    const unsigned short* Bbase = Bt + (size_t)(n0 + wid * 32 + arow) * K + acol;

    for (int k0 = 0; k0 < K; k0 += 32) {
        gload16(Abase + k0, As + (wid * 2) * 512);
        gload16(Abase + k0 + 16 * K, As + (wid * 2 + 1) * 512);
        gload16(Bbase + k0, Bs + (wid * 2) * 512);
        gload16(Bbase + k0 + 16 * K, Bs + (wid * 2 + 1) * 512);
        __syncthreads();
        bf16x8 af[4], bfr[4];
#pragma unroll
        for (int i = 0; i < 4; ++i) {
            af[i] = ld_b8(As + (wr * 64 + i * 16 + (lane & 15)) * 32 + (lane >> 4) * 8);
            bfr[i] = ld_b8(Bs + (wc * 64 + i * 16 + (lane & 15)) * 32 + (lane >> 4) * 8);
        }
#pragma unroll
        for (int i = 0; i < 4; ++i)
#pragma unroll
            for (int j = 0; j < 4; ++j) acc[i][j] = MFMA16(af[i], bfr[j], acc[i][j]);
        __syncthreads();
    }
    const int crow = m0 + wr * 64 + (lane >> 4) * 4;
    const int ccol = n0 + wc * 64 + (lane & 15);
#pragma unroll
    for (int i = 0; i < 4; ++i)
#pragma unroll
        for (int j = 0; j < 4; ++j)
#pragma unroll
            for (int r = 0; r < 4; ++r) {
                const size_t idx = (size_t)(crow + i * 16 + r) * N + ccol + j * 16;
                if (OUTF)
                    ((float*)Cv)[idx] = acc[i][j][r];
                else
                    ((unsigned short*)Cv)[idx] = f2b(acc[i][j][r]);
            }
}

// ---------------- extract V into vt2[bh][t/4][dh][4] from qkv ----------------
__global__ __launch_bounds__(256) void k_vt(const unsigned short* __restrict__ qkv,
                                            unsigned short* __restrict__ vt2) {
    __shared__ unsigned short t_[64][72];
    const int bh = blockIdx.x & 63, tt = blockIdx.x >> 6;
    const int b = bh >> 4, h = bh & 15;
    const int tid = threadIdx.x;
    const int r = tid >> 2, c = (tid & 3) * 16;
    const unsigned short* src =
        qkv + (size_t)(b * T_ + tt * 64 + r) * 3072 + 2048 + h * 64 + c;
    *(u16x8*)&t_[r][c] = *(const u16x8*)src;
    *(u16x8*)&t_[r][c + 8] = *(const u16x8*)(src + 8);
    __syncthreads();
    const int dh = tid & 63, tg = tid >> 6;
    unsigned short* dst = vt2 + (size_t)bh * 131072 + (size_t)(tt * 16) * 256 + dh * 4;
#pragma unroll
    for (int u = 0; u < 4; ++u) {
        const int tq = tg * 4 + u;
        ushort4 o;
        o.x = t_[tq * 4 + 0][dh];
        o.y = t_[tq * 4 + 1][dh];
        o.z = t_[tq * 4 + 2][dh];
        o.w = t_[tq * 4 + 3][dh];
        *(ushort4*)(dst + tq * 256) = o;
    }
}

// ---------------- causal flash attention ----------------
// 4 waves, 64 q-rows per q-tile; each block handles TWO q-tiles (qt = 31-p,
// then p): every block does exactly 33 KV-tiles, grid = 1024.
// Counted-vmcnt pipeline (T3/T4): K depth-2 (3 bufs), V depth-1 (2 bufs),
// raw s_barrier + s_waitcnt vmcnt(6/4/0) -- never drain to 0 mid-loop.
// Swapped QK^T; sigma-PV keeps P entirely in registers (0 bank conflicts).
__global__ __launch_bounds__(256) void k_attn(const unsigned short* __restrict__ qkv,
                                              const unsigned short* __restrict__ vt2,
                                              unsigned short* __restrict__ ao) {
    __shared__ unsigned short Ks[3 * 4096];
    __shared__ unsigned short Vs[2 * 4096];
    const int bh = blockIdx.x & 63;
    const int p = blockIdx.x >> 6;  // 0..15
    const int b = bh >> 4, h = bh & 15;
    const int tid = threadIdx.x, lane = tid & 63, w = tid >> 6;
    const int l4 = lane >> 4, l15 = lane & 15;

    // K staging geometry (XOR-swizzled rows, 16B granule)
    const int sr0 = w * 16 + (lane >> 3);
    const int scol = 8 * ((lane & 7) ^ (lane >> 3));
    const unsigned short* Kg = qkv + (size_t)(b * T_) * 3072 + 1024 + h * 64;

    // V staging: LDS slot s holds global key-quad kq = 4*(s&3)+(s>>2)
    const unsigned short* Vg = vt2 + (size_t)bh * 131072;
    const int s0v = (w * 2 + 0) * 2 + (lane >> 5);
    const int s1v = (w * 2 + 1) * 2 + (lane >> 5);
    const unsigned short* vsrc0 =
        Vg + (4 * (s0v & 3) + (s0v >> 2)) * 256 + (lane & 31) * 8;
    const unsigned short* vsrc1 =
        Vg + (4 * (s1v & 3) + (s1v >> 2)) * 256 + (lane & 31) * 8;

    for (int half = 0; half < 2; ++half) {
        const int qt = half ? p : 31 - p;  // heavy tile first

        // Q fragment rows q = w*16 + l15, pre-scaled by (1/sqrt(64))*log2(e)
        const unsigned short* qb =
            qkv + (size_t)(b * T_ + qt * 64 + w * 16 + l15) * 3072 + h * 64;
        bf16x8 qf0, qf1;
        {
            const bf16x8 r0 = ld_b8(qb + l4 * 8);
            const bf16x8 r1 = ld_b8(qb + 32 + l4 * 8);
#pragma unroll
            for (int j = 0; j < 8; ++j) {
                qf0[j] = (__bf16)((float)r0[j] * 0.18033688f);
                qf1[j] = (__bf16)((float)r1[j] * 0.18033688f);
            }
        }

        float m_s = -1e30f, l_s = 0.f;  // stats for q = l15 (replicated over l4)
        f32x4 o[4] = {};                // o[ni][r]: row q=l4*4+r, col dh=ni*16+l15

        auto STAGE_K = [&](int kt, int kb) {
            unsigned short* Kb = Ks + kb * 4096;
            gload16(Kg + (size_t)(kt * 64 + sr0) * 3072 + scol, Kb + (w * 2) * 512);
            gload16(Kg + (size_t)(kt * 64 + sr0 + 8) * 3072 + scol, Kb + (w * 2 + 1) * 512);
        };
        auto STAGE_V = [&](int kt, int vb) {
            unsigned short* Vb = Vs + vb * 4096;
            gload16(vsrc0 + kt * 4096, Vb + (w * 2) * 512);
            gload16(vsrc1 + kt * 4096, Vb + (w * 2 + 1) * 512);
        };

        auto COMPUTE = [&](int kbuf, int vbuf, bool masked) {
            const unsigned short* Kb = Ks + kbuf * 4096;
            const unsigned short* Vb = Vs + vbuf * 4096;
            float tv[4][4];
            __builtin_amdgcn_s_setprio(1);
#pragma unroll
            for (int i = 0; i < 4; ++i) {
                const int key = i * 16 + l15;
                const int sw = (key & 7) << 4;
                const bf16x8 kf0 = ld_b8(Kb + (key * 128 + ((l4 * 16) ^ sw)) / 2);
                const bf16x8 kf1 = ld_b8(Kb + (key * 128 + ((l4 * 16 + 64) ^ sw)) / 2);
                f32x4 sacc = {};
                sacc = MFMA16(kf0, qf0, sacc);
                sacc = MFMA16(kf1, qf1, sacc);
#pragma unroll
                for (int r = 0; r < 4; ++r) tv[i][r] = sacc[r];
            }
            __builtin_amdgcn_s_setprio(0);
            if (masked) {
#pragma unroll
                for (int i = 0; i < 4; ++i)
#pragma unroll
                    for (int r = 0; r < 4; ++r)
                        if (i * 16 + l4 * 4 + r > w * 16 + l15) tv[i][r] = -1e30f;
            }
            float mi[4];
#pragma unroll
            for (int i = 0; i < 4; ++i)
                mi[i] = fmaxf(fmaxf(tv[i][0], tv[i][1]), fmaxf(tv[i][2], tv[i][3]));
            float mx = fmaxf(fmaxf(mi[0], mi[1]), fmaxf(mi[2], mi[3]));
            mx = fmaxf(mx, __shfl_xor(mx, 16));
            mx = fmaxf(mx, __shfl_xor(mx, 32));
            if (__any(mx > m_s + 8.0f)) {  // defer-max
                const float mnew = fmaxf(m_s, mx);
                const float fac = __builtin_amdgcn_exp2f(m_s - mnew);
                m_s = mnew;
                l_s *= fac;
#pragma unroll
                for (int r = 0; r < 4; ++r) {
                    const float fr = __shfl(fac, (l4 << 4) | (l4 * 4 + r));
#pragma unroll
                    for (int ni = 0; ni < 4; ++ni) o[ni][r] *= fr;
                }
            }
            float rs = 0.f;
            unsigned pw[8];  // pw[i*2+c]: P(keys i*16 + l4*4 + 2c, +2c+1), q=l15
#pragma unroll
            for (int i = 0; i < 4; ++i) {
                float pv[4];
#pragma unroll
                for (int r = 0; r < 4; ++r) {
                    pv[r] = __builtin_amdgcn_exp2f(tv[i][r] - m_s);
                    rs += pv[r];
                }
                pw[i * 2 + 0] = cvt_pk(pv[0], pv[1]);
                pw[i * 2 + 1] = cvt_pk(pv[2], pv[3]);
            }
            rs += __shfl_xor(rs, 16);
            rs += __shfl_xor(rs, 32);
            l_s += rs;
            __builtin_amdgcn_s_setprio(1);
#pragma unroll
            for (int st = 0; st < 2; ++st) {
                const u32x4 pk = {pw[st * 4 + 0], pw[st * 4 + 1], pw[st * 4 + 2],
                                  pw[st * 4 + 3]};
                const bf16x8 pf = __builtin_bit_cast(bf16x8, pk);
#pragma unroll
                for (int ni = 0; ni < 4; ++ni) {
                    const unsigned short* vb =
                        Vb + (l4 * 4 + st * 2) * 256 + (ni * 16 + l15) * 4;
                    const u32x2 va = *(const u32x2*)vb;
                    const u32x2 vc = *(const u32x2*)(vb + 256);
                    const u32x4 vv = {va.x, va.y, vc.x, vc.y};
                    const bf16x8 vf = __builtin_bit_cast(bf16x8, vv);
                    o[ni] = MFMA16(pf, vf, o[ni]);
                }
            }
            __builtin_amdgcn_s_setprio(0);
        };

        // barrier: prior half's COMPUTE reads (all waves) must finish before
        // this half's stages overwrite LDS.
        __builtin_amdgcn_s_barrier();
        // prologue: V depth-1, K depth-2 (issue order matters for vmcnt FIFO)
        STAGE_V(0, 0);
        STAGE_K(0, 0);
        if (qt >= 1) STAGE_K(1, 1);
        for (int t = 0; t <= qt; ++t) {
            if (t + 1 <= qt) STAGE_V(t + 1, (t + 1) & 1);
            if (t + 2 <= qt) {
                STAGE_K(t + 2, (t + 2) % 3);
                asm volatile("s_waitcnt vmcnt(6)" ::: "memory");
            } else if (t + 1 <= qt) {
                asm volatile("s_waitcnt vmcnt(4)" ::: "memory");
            } else {
                asm volatile("s_waitcnt vmcnt(0)" ::: "memory");
            }
            __builtin_amdgcn_sched_barrier(0);
            __builtin_amdgcn_s_barrier();
            __builtin_amdgcn_sched_barrier(0);
            COMPUTE(t % 3, t & 1, t == qt);
        }

        // epilogue: fetch per-row l via shfl, normalize, store bf16 [b,t,h,dh]
        unsigned short* aop = ao + (size_t)(b * T_ + qt * 64 + w * 16) * 1024 + h * 64;
#pragma unroll
        for (int r = 0; r < 4; ++r) {
            const float lr = __shfl(l_s, (l4 << 4) | (l4 * 4 + r));
            const float inv = 1.0f / lr;
#pragma unroll
            for (int ni = 0; ni < 4; ++ni)
                aop[(size_t)(l4 * 4 + r) * 1024 + ni * 16 + l15] = f2b(o[ni][r] * inv);
        }
    }
}

extern "C" void kernel_launch(void* const* d_in, const int* in_sizes, int n_in,
                              void* d_out, int out_size, void* d_ws, size_t ws_size,
                              hipStream_t stream) {
    (void)in_sizes; (void)n_in; (void)out_size; (void)ws_size;
    const float* x = (const float*)d_in[0];
    const float* Wqkv = (const float*)d_in[1];
    const float* Wout = (const float*)d_in[2];
    char* ws = (char*)d_ws;
    unsigned short* xb = (unsigned short*)(ws + 0);             // 16 MB
    unsigned short* wqkvT = (unsigned short*)(ws + 16777216);   // 6 MB  (3072 x 1024)
    unsigned short* woutT = (unsigned short*)(ws + 23068672);   // 2 MB  (1024 x 1024)
    unsigned short* qkvb = (unsigned short*)(ws + 25165824);    // 48 MB (8192 x 3072)
    unsigned short* vt2 = (unsigned short*)(ws + 75497472);     // 16 MB (64 x 512 x 64 x 4)
    unsigned short* ao = (unsigned short*)(ws + 92274688);      // 16 MB (8192 x 1024)

    k_cvt<<<2048, 256, 0, stream>>>(x, xb, 4 * T_ * 1024);
    k_cvt_T<1024, 3072><<<16 * 48, 256, 0, stream>>>(Wqkv, wqkvT);
    k_cvt_T<1024, 1024><<<16 * 16, 256, 0, stream>>>(Wout, woutT);
    k_gemm<1024, 0><<<dim3(24, 64), 256, 0, stream>>>(xb, wqkvT, (void*)qkvb, 3072);
    k_vt<<<2048, 256, 0, stream>>>(qkvb, vt2);
    k_attn<<<1024, 256, 0, stream>>>(qkvb, vt2, ao);
    k_gemm<1024, 1><<<dim3(8, 64), 256, 0, stream>>>(ao, woutT, d_out, 1024);
}

// Round 6
// 192.145 us; speedup vs baseline: 1.0284x; 1.0284x over previous
//
#include <hip/hip_runtime.h>
#include <stdint.h>

#define T_ 2048
#define BB_ 4

typedef __bf16 bf16x8 __attribute__((ext_vector_type(8)));
typedef float f32x4 __attribute__((ext_vector_type(4)));
typedef unsigned short u16x8 __attribute__((ext_vector_type(8)));
typedef unsigned int u32x2 __attribute__((ext_vector_type(2)));
typedef unsigned int u32x4 __attribute__((ext_vector_type(4)));

__device__ __forceinline__ unsigned short f2b(float f) {
    unsigned int u = __builtin_bit_cast(unsigned int, f);
    return (unsigned short)((u + 0x7fffu + ((u >> 16) & 1u)) >> 16);
}

__device__ __forceinline__ unsigned cvt_pk(float lo, float hi) {
    unsigned r;
    asm("v_cvt_pk_bf16_f32 %0, %1, %2" : "=v"(r) : "v"(lo), "v"(hi));
    return r;
}

__device__ __forceinline__ void gload16(const void* g, const void* lds) {
    __builtin_amdgcn_global_load_lds(
        (__attribute__((address_space(1))) void*)(uintptr_t)g,
        (__attribute__((address_space(3))) void*)(uintptr_t)(unsigned int)(uintptr_t)lds,
        16, 0, 0);
}

__device__ __forceinline__ bf16x8 ld_b8(const unsigned short* p) {
    return *(const bf16x8*)p;
}

#define MFMA16(a, b, c) __builtin_amdgcn_mfma_f32_16x16x32_bf16((a), (b), (c), 0, 0, 0)

// ---------------- fp32 -> bf16 elementwise ----------------
__global__ __launch_bounds__(256) void k_cvt(const float* __restrict__ in,
                                             unsigned short* __restrict__ out, int n) {
    int i = (blockIdx.x * 256 + threadIdx.x) * 4;
    const int stride = gridDim.x * 256 * 4;
    for (; i < n; i += stride) {
        const float4 v = *(const float4*)(in + i);
        ushort4 o = make_ushort4(f2b(v.x), f2b(v.y), f2b(v.z), f2b(v.w));
        *(ushort4*)(out + i) = o;
    }
}

// ---------------- fp32 (K x N) -> bf16 transposed (N x K) ----------------
template <int K, int N>
__global__ __launch_bounds__(256) void k_cvt_T(const float* __restrict__ W,
                                               unsigned short* __restrict__ WT) {
    __shared__ unsigned short t_[64][72];
    const int nt = blockIdx.x % (N / 64), kt = blockIdx.x / (N / 64);
    const int tid = threadIdx.x;
    const int r = tid >> 2, c = (tid & 3) * 16;
    const float* src = W + (size_t)(kt * 64 + r) * N + nt * 64 + c;
#pragma unroll
    for (int j = 0; j < 16; j += 4) {
        float4 v = *(const float4*)(src + j);
        t_[r][c + j + 0] = f2b(v.x);
        t_[r][c + j + 1] = f2b(v.y);
        t_[r][c + j + 2] = f2b(v.z);
        t_[r][c + j + 3] = f2b(v.w);
    }
    __syncthreads();
    unsigned short* dst = WT + (size_t)(nt * 64 + r) * K + kt * 64 + c;
#pragma unroll
    for (int j = 0; j < 16; ++j) dst[j] = t_[c + j][r];
}

// ---------------- 256x256 BK=64 8-wave pipelined GEMM (qkv projection) -----
// C[M][3072] = A[M][1024] * Bt[3072][1024]^T.  N-tiles >= 2048 (V third)
// are scattered directly into vt2[bh][t/4][dh][4] (replaces k_vt).
// T2: st-swizzle (byte ^= (row&4)<<3) on LDS, pre-swizzled gload source.
// T3/T4: 2-tile-deep prefetch, vmcnt(8) mid-loop (never 0). T5: setprio.
__global__ __launch_bounds__(512, 2) void k_gemm256(
    const unsigned short* __restrict__ A, const unsigned short* __restrict__ Bt,
    unsigned short* __restrict__ qkv, unsigned short* __restrict__ vt2) {
    constexpr int K = 1024, NT = K / 64;
    __shared__ unsigned short Abuf[2][2][8192];  // [dbuf][half 128 rows][128x64]
    __shared__ unsigned short Bbuf[2][2][8192];
    const int tid = threadIdx.x;
    const int lane = tid & 63, wid = tid >> 6;
    const int wr = wid >> 2, wc = wid & 3;  // wave tile: rows wr*128, cols wc*64
    const int l4 = lane >> 4, l15 = lane & 15;
    const int m0 = blockIdx.y * 256, n0 = blockIdx.x * 256;

    // staging geometry: thread covers LDS short-offsets tid*8 and tid*8+4096
    const int se0 = tid * 8, se1 = tid * 8 + 4096;
    const int sr0_ = se0 >> 6, sc0_ = (se0 & 63) ^ ((sr0_ & 4) ? 16 : 0);
    const int sr1_ = se1 >> 6, sc1_ = (se1 & 63) ^ ((sr1_ & 4) ? 16 : 0);

    f32x4 acc[8][4] = {};

    auto STAGE = [&](int t, int d) {
#pragma unroll
        for (int h = 0; h < 2; ++h) {
            const unsigned short* as = A + (size_t)(m0 + h * 128) * K + t * 64;
            gload16(as + (size_t)sr0_ * K + sc0_, &Abuf[d][h][se0]);
            gload16(as + (size_t)sr1_ * K + sc1_, &Abuf[d][h][se1]);
        }
#pragma unroll
        for (int h = 0; h < 2; ++h) {
            const unsigned short* bs = Bt + (size_t)(n0 + h * 128) * K + t * 64;
            gload16(bs + (size_t)sr0_ * K + sc0_, &Bbuf[d][h][se0]);
            gload16(bs + (size_t)sr1_ * K + sc1_, &Bbuf[d][h][se1]);
        }
    };

    auto swz = [&](const unsigned short* base, int row, int col) {
        int byte = row * 128 + col * 2;
        byte ^= (row & 4) << 3;
        return (const unsigned short*)((const char*)base + byte);
    };

    STAGE(0, 0);
    STAGE(1, 1);
    for (int t = 0; t < NT; ++t) {
        if (t == NT - 1)
            asm volatile("s_waitcnt vmcnt(0)" ::: "memory");
        else
            asm volatile("s_waitcnt vmcnt(8)" ::: "memory");
        __builtin_amdgcn_sched_barrier(0);
        __builtin_amdgcn_s_barrier();
        __builtin_amdgcn_sched_barrier(0);
        const unsigned short* Ah = &Abuf[t & 1][wr][0];
        const unsigned short* Bh = &Bbuf[t & 1][wc >> 1][0];
#pragma unroll
        for (int q = 0; q < 4; ++q) {
            const int qm = q & 1, qn = q >> 1;
            bf16x8 af[4][2], bfr[2][2];
#pragma unroll
            for (int m = 0; m < 4; ++m)
#pragma unroll
                for (int ks = 0; ks < 2; ++ks)
                    af[m][ks] = ld_b8(swz(Ah, qm * 64 + m * 16 + l15, ks * 32 + l4 * 8));
#pragma unroll
            for (int nn = 0; nn < 2; ++nn)
#pragma unroll
                for (int ks = 0; ks < 2; ++ks)
                    bfr[nn][ks] = ld_b8(
                        swz(Bh, (wc & 1) * 64 + qn * 32 + nn * 16 + l15, ks * 32 + l4 * 8));
            __builtin_amdgcn_s_setprio(1);
#pragma unroll
            for (int m = 0; m < 4; ++m)
#pragma unroll
                for (int nn = 0; nn < 2; ++nn)
#pragma unroll
                    for (int ks = 0; ks < 2; ++ks)
                        acc[qm * 4 + m][qn * 2 + nn] =
                            MFMA16(af[m][ks], bfr[nn][ks], acc[qm * 4 + m][qn * 2 + nn]);
            __builtin_amdgcn_s_setprio(0);
            __builtin_amdgcn_sched_barrier(0);
        }
        __builtin_amdgcn_s_barrier();
        __builtin_amdgcn_sched_barrier(0);
        if (t + 2 < NT) STAGE(t + 2, t & 1);
    }

    // epilogue
    const int crow0 = m0 + wr * 128 + l4 * 4;
    const int ccol0 = n0 + wc * 64 + l15;
    if (n0 >= 2048) {  // V third -> vt2[bh][t/4][dh][4]
#pragma unroll
        for (int m = 0; m < 8; ++m)
#pragma unroll
            for (int n = 0; n < 4; ++n)
#pragma unroll
                for (int r = 0; r < 4; ++r) {
                    const int row = crow0 + m * 16 + r;
                    const int c = ccol0 + n * 16 - 2048;
                    const int b = row >> 11, tt = row & 2047;
                    const int h = c >> 6, dh = c & 63;
                    vt2[(size_t)(b * 16 + h) * 131072 + (tt >> 2) * 256 + dh * 4 +
                        (tt & 3)] = f2b(acc[m][n][r]);
                }
    } else {
#pragma unroll
        for (int m = 0; m < 8; ++m)
#pragma unroll
            for (int n = 0; n < 4; ++n)
#pragma unroll
                for (int r = 0; r < 4; ++r)
                    qkv[(size_t)(crow0 + m * 16 + r) * 3072 + ccol0 + n * 16] =
                        f2b(acc[m][n][r]);
    }
}

// ---------------- bf16 GEMM: C[M][N] = A[M][K] * Bt[N][K]^T (128^2) --------
template <int K, int OUTF>
__global__ __launch_bounds__(256) void k_gemm(const unsigned short* __restrict__ A,
                                              const unsigned short* __restrict__ Bt,
                                              void* __restrict__ Cv, int N) {
    __shared__ unsigned short As[128 * 32];
    __shared__ unsigned short Bs[128 * 32];
    const int tid = threadIdx.x;
    const int lane = tid & 63;
    const int wid = tid >> 6;
    const int wr = wid >> 1, wc = wid & 1;
    const int m0 = blockIdx.y * 128, n0 = blockIdx.x * 128;
    const int arow = lane >> 2;
    const int acol = (lane & 3) * 8;
    f32x4 acc[4][4] = {};

    const unsigned short* Abase = A + (size_t)(m0 + wid * 32 + arow) * K + acol;
    const unsigned short* Bbase = Bt + (size_t)(n0 + wid * 32 + arow) * K + acol;

    for (int k0 = 0; k0 < K; k0 += 32) {
        gload16(Abase + k0, As + (wid * 2) * 512);
        gload16(Abase + k0 + 16 * K, As + (wid * 2 + 1) * 512);
        gload16(Bbase + k0, Bs + (wid * 2) * 512);
        gload16(Bbase + k0 + 16 * K, Bs + (wid * 2 + 1) * 512);
        __syncthreads();
        bf16x8 af[4], bfr[4];
#pragma unroll
        for (int i = 0; i < 4; ++i) {
            af[i] = ld_b8(As + (wr * 64 + i * 16 + (lane & 15)) * 32 + (lane >> 4) * 8);
            bfr[i] = ld_b8(Bs + (wc * 64 + i * 16 + (lane & 15)) * 32 + (lane >> 4) * 8);
        }
#pragma unroll
        for (int i = 0; i < 4; ++i)
#pragma unroll
            for (int j = 0; j < 4; ++j) acc[i][j] = MFMA16(af[i], bfr[j], acc[i][j]);
        __syncthreads();
    }
    const int crow = m0 + wr * 64 + (lane >> 4) * 4;
    const int ccol = n0 + wc * 64 + (lane & 15);
#pragma unroll
    for (int i = 0; i < 4; ++i)
#pragma unroll
        for (int j = 0; j < 4; ++j)
#pragma unroll
            for (int r = 0; r < 4; ++r) {
                const size_t idx = (size_t)(crow + i * 16 + r) * N + ccol + j * 16;
                if (OUTF)
                    ((float*)Cv)[idx] = acc[i][j][r];
                else
                    ((unsigned short*)Cv)[idx] = f2b(acc[i][j][r]);
            }
}

// ---------------- causal flash attention (round-4 proven version) ----------
__global__ __launch_bounds__(256) void k_attn(const unsigned short* __restrict__ qkv,
                                              const unsigned short* __restrict__ vt2,
                                              unsigned short* __restrict__ ao) {
    __shared__ unsigned short Ks[2 * 4096];
    __shared__ unsigned short Vs[2 * 4096];
    const int bh = blockIdx.x & 63;
    const int p = blockIdx.x >> 6;  // 0..15
    const int b = bh >> 4, h = bh & 15;
    const int tid = threadIdx.x, lane = tid & 63, w = tid >> 6;
    const int l4 = lane >> 4, l15 = lane & 15;

    const int sr0 = w * 16 + (lane >> 3);
    const int scol = 8 * ((lane & 7) ^ (lane >> 3));
    const unsigned short* Kg = qkv + (size_t)(b * T_) * 3072 + 1024 + h * 64;

    const unsigned short* Vg = vt2 + (size_t)bh * 131072;
    const int s0v = (w * 2 + 0) * 2 + (lane >> 5);
    const int s1v = (w * 2 + 1) * 2 + (lane >> 5);
    const unsigned short* vsrc0 =
        Vg + (4 * (s0v & 3) + (s0v >> 2)) * 256 + (lane & 31) * 8;
    const unsigned short* vsrc1 =
        Vg + (4 * (s1v & 3) + (s1v >> 2)) * 256 + (lane & 31) * 8;

    for (int half = 0; half < 2; ++half) {
        const int qt = half ? p : 31 - p;  // heavy tile first

        const unsigned short* qb =
            qkv + (size_t)(b * T_ + qt * 64 + w * 16 + l15) * 3072 + h * 64;
        bf16x8 qf0, qf1;
        {
            const bf16x8 r0 = ld_b8(qb + l4 * 8);
            const bf16x8 r1 = ld_b8(qb + 32 + l4 * 8);
#pragma unroll
            for (int j = 0; j < 8; ++j) {
                qf0[j] = (__bf16)((float)r0[j] * 0.18033688f);
                qf1[j] = (__bf16)((float)r1[j] * 0.18033688f);
            }
        }

        float m_s = -1e30f, l_s = 0.f;
        f32x4 o[4] = {};

        auto STAGE = [&](int kt, int bi) {
            unsigned short* Kb = Ks + bi * 4096;
            unsigned short* Vb = Vs + bi * 4096;
            gload16(Kg + (size_t)(kt * 64 + sr0) * 3072 + scol, Kb + (w * 2) * 512);
            gload16(Kg + (size_t)(kt * 64 + sr0 + 8) * 3072 + scol, Kb + (w * 2 + 1) * 512);
            gload16(vsrc0 + kt * 4096, Vb + (w * 2) * 512);
            gload16(vsrc1 + kt * 4096, Vb + (w * 2 + 1) * 512);
        };

        auto COMPUTE = [&](int bi, bool masked) {
            const unsigned short* Kb = Ks + bi * 4096;
            const unsigned short* Vb = Vs + bi * 4096;
            float tv[4][4];
            __builtin_amdgcn_s_setprio(1);
#pragma unroll
            for (int i = 0; i < 4; ++i) {
                const int key = i * 16 + l15;
                const int sw = (key & 7) << 4;
                const bf16x8 kf0 = ld_b8(Kb + (key * 128 + ((l4 * 16) ^ sw)) / 2);
                const bf16x8 kf1 = ld_b8(Kb + (key * 128 + ((l4 * 16 + 64) ^ sw)) / 2);
                f32x4 sacc = {};
                sacc = MFMA16(kf0, qf0, sacc);
                sacc = MFMA16(kf1, qf1, sacc);
#pragma unroll
                for (int r = 0; r < 4; ++r) tv[i][r] = sacc[r];
            }
            __builtin_amdgcn_s_setprio(0);
            if (masked) {
#pragma unroll
                for (int i = 0; i < 4; ++i)
#pragma unroll
                    for (int r = 0; r < 4; ++r)
                        if (i * 16 + l4 * 4 + r > w * 16 + l15) tv[i][r] = -1e30f;
            }
            float mi[4];
#pragma unroll
            for (int i = 0; i < 4; ++i)
                mi[i] = fmaxf(fmaxf(tv[i][0], tv[i][1]), fmaxf(tv[i][2], tv[i][3]));
            float mx = fmaxf(fmaxf(mi[0], mi[1]), fmaxf(mi[2], mi[3]));
            mx = fmaxf(mx, __shfl_xor(mx, 16));
            mx = fmaxf(mx, __shfl_xor(mx, 32));
            if (__any(mx > m_s + 8.0f)) {  // defer-max
                const float mnew = fmaxf(m_s, mx);
                const float fac = __builtin_amdgcn_exp2f(m_s - mnew);
                m_s = mnew;
                l_s *= fac;
#pragma unroll
                for (int r = 0; r < 4; ++r) {
                    const float fr = __shfl(fac, (l4 << 4) | (l4 * 4 + r));
#pragma unroll
                    for (int ni = 0; ni < 4; ++ni) o[ni][r] *= fr;
                }
            }
            float rs = 0.f;
            unsigned pw[8];
#pragma unroll
            for (int i = 0; i < 4; ++i) {
                float pv[4];
#pragma unroll
                for (int r = 0; r < 4; ++r) {
                    pv[r] = __builtin_amdgcn_exp2f(tv[i][r] - m_s);
                    rs += pv[r];
                }
                pw[i * 2 + 0] = cvt_pk(pv[0], pv[1]);
                pw[i * 2 + 1] = cvt_pk(pv[2], pv[3]);
            }
            rs += __shfl_xor(rs, 16);
            rs += __shfl_xor(rs, 32);
            l_s += rs;
            __builtin_amdgcn_s_setprio(1);
#pragma unroll
            for (int st = 0; st < 2; ++st) {
                const u32x4 pk = {pw[st * 4 + 0], pw[st * 4 + 1], pw[st * 4 + 2],
                                  pw[st * 4 + 3]};
                const bf16x8 pf = __builtin_bit_cast(bf16x8, pk);
#pragma unroll
                for (int ni = 0; ni < 4; ++ni) {
                    const unsigned short* vb =
                        Vb + (l4 * 4 + st * 2) * 256 + (ni * 16 + l15) * 4;
                    const u32x2 va = *(const u32x2*)vb;
                    const u32x2 vc = *(const u32x2*)(vb + 256);
                    const u32x4 vv = {va.x, va.y, vc.x, vc.y};
                    const bf16x8 vf = __builtin_bit_cast(bf16x8, vv);
                    o[ni] = MFMA16(pf, vf, o[ni]);
                }
            }
            __builtin_amdgcn_s_setprio(0);
        };

        __syncthreads();
        STAGE(0, 0);
        __syncthreads();
        for (int kt = 0; kt < qt; ++kt) {
            STAGE(kt + 1, (kt + 1) & 1);
            COMPUTE(kt & 1, false);
            __syncthreads();
        }
        COMPUTE(qt & 1, true);

        unsigned short* aop = ao + (size_t)(b * T_ + qt * 64 + w * 16) * 1024 + h * 64;
#pragma unroll
        for (int r = 0; r < 4; ++r) {
            const float lr = __shfl(l_s, (l4 << 4) | (l4 * 4 + r));
            const float inv = 1.0f / lr;
#pragma unroll
            for (int ni = 0; ni < 4; ++ni)
                aop[(size_t)(l4 * 4 + r) * 1024 + ni * 16 + l15] = f2b(o[ni][r] * inv);
        }
    }
}

extern "C" void kernel_launch(void* const* d_in, const int* in_sizes, int n_in,
                              void* d_out, int out_size, void* d_ws, size_t ws_size,
                              hipStream_t stream) {
    (void)in_sizes; (void)n_in; (void)out_size; (void)ws_size;
    const float* x = (const float*)d_in[0];
    const float* Wqkv = (const float*)d_in[1];
    const float* Wout = (const float*)d_in[2];
    char* ws = (char*)d_ws;
    unsigned short* xb = (unsigned short*)(ws + 0);             // 16 MB
    unsigned short* wqkvT = (unsigned short*)(ws + 16777216);   // 6 MB  (3072 x 1024)
    unsigned short* woutT = (unsigned short*)(ws + 23068672);   // 2 MB  (1024 x 1024)
    unsigned short* qkvb = (unsigned short*)(ws + 25165824);    // 48 MB (8192 x 3072, V third unused)
    unsigned short* vt2 = (unsigned short*)(ws + 75497472);     // 16 MB (64 x 512 x 64 x 4)
    unsigned short* ao = (unsigned short*)(ws + 92274688);      // 16 MB (8192 x 1024)

    k_cvt<<<2048, 256, 0, stream>>>(x, xb, 4 * T_ * 1024);
    k_cvt_T<1024, 3072><<<16 * 48, 256, 0, stream>>>(Wqkv, wqkvT);
    k_cvt_T<1024, 1024><<<16 * 16, 256, 0, stream>>>(Wout, woutT);
    k_gemm256<<<dim3(12, 32), 512, 0, stream>>>(xb, wqkvT, qkvb, vt2);
    k_attn<<<1024, 256, 0, stream>>>(qkvb, vt2, ao);
    k_gemm<1024, 1><<<dim3(8, 64), 256, 0, stream>>>(ao, woutT, d_out, 1024);
}

// Round 7
// 168.261 us; speedup vs baseline: 1.1744x; 1.1419x over previous
//
#include <hip/hip_runtime.h>
#include <stdint.h>

#define T_ 2048
#define BB_ 4

typedef __bf16 bf16x8 __attribute__((ext_vector_type(8)));
typedef float f32x4 __attribute__((ext_vector_type(4)));
typedef unsigned short u16x8 __attribute__((ext_vector_type(8)));
typedef unsigned int u32x2 __attribute__((ext_vector_type(2)));
typedef unsigned int u32x4 __attribute__((ext_vector_type(4)));

__device__ __forceinline__ unsigned short f2b(float f) {
    unsigned int u = __builtin_bit_cast(unsigned int, f);
    return (unsigned short)((u + 0x7fffu + ((u >> 16) & 1u)) >> 16);
}

__device__ __forceinline__ unsigned cvt_pk(float lo, float hi) {
    unsigned r;
    asm("v_cvt_pk_bf16_f32 %0, %1, %2" : "=v"(r) : "v"(lo), "v"(hi));
    return r;
}

__device__ __forceinline__ void gload16(const void* g, const void* lds) {
    __builtin_amdgcn_global_load_lds(
        (__attribute__((address_space(1))) void*)(uintptr_t)g,
        (__attribute__((address_space(3))) void*)(uintptr_t)(unsigned int)(uintptr_t)lds,
        16, 0, 0);
}

__device__ __forceinline__ bf16x8 ld_b8(const unsigned short* p) {
    return *(const bf16x8*)p;
}

#define MFMA16(a, b, c) __builtin_amdgcn_mfma_f32_16x16x32_bf16((a), (b), (c), 0, 0, 0)

// ---------------- fp32 -> bf16 elementwise ----------------
__global__ __launch_bounds__(256) void k_cvt(const float* __restrict__ in,
                                             unsigned short* __restrict__ out, int n) {
    int i = (blockIdx.x * 256 + threadIdx.x) * 4;
    const int stride = gridDim.x * 256 * 4;
    for (; i < n; i += stride) {
        const float4 v = *(const float4*)(in + i);
        ushort4 o = make_ushort4(f2b(v.x), f2b(v.y), f2b(v.z), f2b(v.w));
        *(ushort4*)(out + i) = o;
    }
}

// ---------------- fp32 (K x N) -> bf16 transposed (N x K) ----------------
template <int K, int N>
__global__ __launch_bounds__(256) void k_cvt_T(const float* __restrict__ W,
                                               unsigned short* __restrict__ WT) {
    __shared__ unsigned short t_[64][72];
    const int nt = blockIdx.x % (N / 64), kt = blockIdx.x / (N / 64);
    const int tid = threadIdx.x;
    const int r = tid >> 2, c = (tid & 3) * 16;
    const float* src = W + (size_t)(kt * 64 + r) * N + nt * 64 + c;
#pragma unroll
    for (int j = 0; j < 16; j += 4) {
        float4 v = *(const float4*)(src + j);
        t_[r][c + j + 0] = f2b(v.x);
        t_[r][c + j + 1] = f2b(v.y);
        t_[r][c + j + 2] = f2b(v.z);
        t_[r][c + j + 3] = f2b(v.w);
    }
    __syncthreads();
    unsigned short* dst = WT + (size_t)(nt * 64 + r) * K + kt * 64 + c;
#pragma unroll
    for (int j = 0; j < 16; ++j) dst[j] = t_[c + j][r];
}

// ---------------- 256x128 BK=64 8-wave pipelined GEMM ----------------------
// MODE 0: C = qkv bf16 [M][3072]; N-tiles >= 2048 (V third) scatter into
//         vt2[bh][t/4][dh][4].   grid (24, 32) = 768 = 3 x 256 CUs.
// MODE 1: C = float [M][1024].   grid (8, 32)  = 256 = 1 x 256 CUs.
// LDS 96 KiB -> 1 block/CU. T2: 3-bit swizzle byte^=(row&7)<<4 (0-conflict,
// proven in k_attn). T3/T4: depth-2 prefetch, vmcnt(6) mid-loop. T5: setprio.
template <int MODE, int NCOLS>
__global__ __launch_bounds__(512, 2) void k_gemm256(
    const unsigned short* __restrict__ A, const unsigned short* __restrict__ Bt,
    void* __restrict__ Cv, unsigned short* __restrict__ vt2) {
    constexpr int K = 1024, NT = K / 64;
    __shared__ unsigned short Abuf[2][2][8192];  // [dbuf][row-half][128x64]
    __shared__ unsigned short Bbuf[2][8192];     // [dbuf][128x64]
    const int tid = threadIdx.x;
    const int lane = tid & 63, wid = tid >> 6;
    const int wr = wid >> 1, wc = wid & 1;  // wave tile: rows wr*64, cols wc*64
    const int l4 = lane >> 4, l15 = lane & 15;
    const int m0 = blockIdx.y * 256, n0 = blockIdx.x * 128;

    // staging geometry: thread covers LDS short-offsets tid*8 and tid*8+4096
    const int se0 = tid * 8, se1 = tid * 8 + 4096;
    const int r0_ = se0 >> 6, c0_ = (se0 & 63) ^ ((r0_ & 7) << 3);
    const int r1_ = se1 >> 6, c1_ = (se1 & 63) ^ ((r1_ & 7) << 3);

    f32x4 acc[4][4] = {};

    auto STAGE = [&](int t, int d) {
#pragma unroll
        for (int h = 0; h < 2; ++h) {
            const unsigned short* as = A + (size_t)(m0 + h * 128) * K + t * 64;
            gload16(as + (size_t)r0_ * K + c0_, &Abuf[d][h][se0]);
            gload16(as + (size_t)r1_ * K + c1_, &Abuf[d][h][se1]);
        }
        const unsigned short* bs = Bt + (size_t)n0 * K + t * 64;
        gload16(bs + (size_t)r0_ * K + c0_, &Bbuf[d][se0]);
        gload16(bs + (size_t)r1_ * K + c1_, &Bbuf[d][se1]);
    };

    auto swz = [](const unsigned short* base, int row, int col) {
        int byte = row * 128 + col * 2;
        byte ^= (row & 7) << 4;
        return (const unsigned short*)((const char*)base + byte);
    };

    STAGE(0, 0);
    STAGE(1, 1);
    for (int t = 0; t < NT; ++t) {
        if (t == NT - 1)
            asm volatile("s_waitcnt vmcnt(0)" ::: "memory");
        else
            asm volatile("s_waitcnt vmcnt(6)" ::: "memory");
        __builtin_amdgcn_sched_barrier(0);
        __builtin_amdgcn_s_barrier();
        __builtin_amdgcn_sched_barrier(0);
        const unsigned short* Ah = &Abuf[t & 1][wr >> 1][0];
        const unsigned short* Bh = &Bbuf[t & 1][0];
#pragma unroll
        for (int ks = 0; ks < 2; ++ks) {
            bf16x8 af[4], bfr[4];
#pragma unroll
            for (int m = 0; m < 4; ++m)
                af[m] = ld_b8(swz(Ah, (wr & 1) * 64 + m * 16 + l15, ks * 32 + l4 * 8));
#pragma unroll
            for (int n = 0; n < 4; ++n)
                bfr[n] = ld_b8(swz(Bh, wc * 64 + n * 16 + l15, ks * 32 + l4 * 8));
            __builtin_amdgcn_s_setprio(1);
#pragma unroll
            for (int m = 0; m < 4; ++m)
#pragma unroll
                for (int n = 0; n < 4; ++n)
                    acc[m][n] = MFMA16(af[m], bfr[n], acc[m][n]);
            __builtin_amdgcn_s_setprio(0);
            __builtin_amdgcn_sched_barrier(0);
        }
        __builtin_amdgcn_s_barrier();
        __builtin_amdgcn_sched_barrier(0);
        if (t + 2 < NT) STAGE(t + 2, t & 1);
    }

    // epilogue
    const int crow0 = m0 + wr * 64 + l4 * 4;
    const int ccol0 = n0 + wc * 64 + l15;
    if (MODE == 0 && n0 >= 2048) {  // V third -> vt2[bh][t/4][dh][4]
#pragma unroll
        for (int m = 0; m < 4; ++m)
#pragma unroll
            for (int n = 0; n < 4; ++n) {
                const int row = crow0 + m * 16;  // rows row..row+3 contiguous
                const int c = ccol0 + n * 16 - 2048;
                const int b = row >> 11, tt = row & 2047;
                const int h = c >> 6, dh = c & 63;
                ushort4 o;
                o.x = f2b(acc[m][n][0]);
                o.y = f2b(acc[m][n][1]);
                o.z = f2b(acc[m][n][2]);
                o.w = f2b(acc[m][n][3]);
                *(ushort4*)(vt2 + (size_t)(b * 16 + h) * 131072 + (tt >> 2) * 256 +
                            dh * 4) = o;
            }
    } else {
#pragma unroll
        for (int m = 0; m < 4; ++m)
#pragma unroll
            for (int n = 0; n < 4; ++n)
#pragma unroll
                for (int r = 0; r < 4; ++r) {
                    const size_t idx =
                        (size_t)(crow0 + m * 16 + r) * NCOLS + ccol0 + n * 16;
                    if (MODE == 1)
                        ((float*)Cv)[idx] = acc[m][n][r];
                    else
                        ((unsigned short*)Cv)[idx] = f2b(acc[m][n][r]);
                }
    }
}

// ---------------- causal flash attention (round-4 proven version) ----------
__global__ __launch_bounds__(256) void k_attn(const unsigned short* __restrict__ qkv,
                                              const unsigned short* __restrict__ vt2,
                                              unsigned short* __restrict__ ao) {
    __shared__ unsigned short Ks[2 * 4096];
    __shared__ unsigned short Vs[2 * 4096];
    const int bh = blockIdx.x & 63;
    const int p = blockIdx.x >> 6;  // 0..15
    const int b = bh >> 4, h = bh & 15;
    const int tid = threadIdx.x, lane = tid & 63, w = tid >> 6;
    const int l4 = lane >> 4, l15 = lane & 15;

    const int sr0 = w * 16 + (lane >> 3);
    const int scol = 8 * ((lane & 7) ^ (lane >> 3));
    const unsigned short* Kg = qkv + (size_t)(b * T_) * 3072 + 1024 + h * 64;

    const unsigned short* Vg = vt2 + (size_t)bh * 131072;
    const int s0v = (w * 2 + 0) * 2 + (lane >> 5);
    const int s1v = (w * 2 + 1) * 2 + (lane >> 5);
    const unsigned short* vsrc0 =
        Vg + (4 * (s0v & 3) + (s0v >> 2)) * 256 + (lane & 31) * 8;
    const unsigned short* vsrc1 =
        Vg + (4 * (s1v & 3) + (s1v >> 2)) * 256 + (lane & 31) * 8;

    for (int half = 0; half < 2; ++half) {
        const int qt = half ? p : 31 - p;  // heavy tile first

        const unsigned short* qb =
            qkv + (size_t)(b * T_ + qt * 64 + w * 16 + l15) * 3072 + h * 64;
        bf16x8 qf0, qf1;
        {
            const bf16x8 r0 = ld_b8(qb + l4 * 8);
            const bf16x8 r1 = ld_b8(qb + 32 + l4 * 8);
#pragma unroll
            for (int j = 0; j < 8; ++j) {
                qf0[j] = (__bf16)((float)r0[j] * 0.18033688f);
                qf1[j] = (__bf16)((float)r1[j] * 0.18033688f);
            }
        }

        float m_s = -1e30f, l_s = 0.f;
        f32x4 o[4] = {};

        auto STAGE = [&](int kt, int bi) {
            unsigned short* Kb = Ks + bi * 4096;
            unsigned short* Vb = Vs + bi * 4096;
            gload16(Kg + (size_t)(kt * 64 + sr0) * 3072 + scol, Kb + (w * 2) * 512);
            gload16(Kg + (size_t)(kt * 64 + sr0 + 8) * 3072 + scol, Kb + (w * 2 + 1) * 512);
            gload16(vsrc0 + kt * 4096, Vb + (w * 2) * 512);
            gload16(vsrc1 + kt * 4096, Vb + (w * 2 + 1) * 512);
        };

        auto COMPUTE = [&](int bi, bool masked) {
            const unsigned short* Kb = Ks + bi * 4096;
            const unsigned short* Vb = Vs + bi * 4096;
            float tv[4][4];
            __builtin_amdgcn_s_setprio(1);
#pragma unroll
            for (int i = 0; i < 4; ++i) {
                const int key = i * 16 + l15;
                const int sw = (key & 7) << 4;
                const bf16x8 kf0 = ld_b8(Kb + (key * 128 + ((l4 * 16) ^ sw)) / 2);
                const bf16x8 kf1 = ld_b8(Kb + (key * 128 + ((l4 * 16 + 64) ^ sw)) / 2);
                f32x4 sacc = {};
                sacc = MFMA16(kf0, qf0, sacc);
                sacc = MFMA16(kf1, qf1, sacc);
#pragma unroll
                for (int r = 0; r < 4; ++r) tv[i][r] = sacc[r];
            }
            __builtin_amdgcn_s_setprio(0);
            if (masked) {
#pragma unroll
                for (int i = 0; i < 4; ++i)
#pragma unroll
                    for (int r = 0; r < 4; ++r)
                        if (i * 16 + l4 * 4 + r > w * 16 + l15) tv[i][r] = -1e30f;
            }
            float mi[4];
#pragma unroll
            for (int i = 0; i < 4; ++i)
                mi[i] = fmaxf(fmaxf(tv[i][0], tv[i][1]), fmaxf(tv[i][2], tv[i][3]));
            float mx = fmaxf(fmaxf(mi[0], mi[1]), fmaxf(mi[2], mi[3]));
            mx = fmaxf(mx, __shfl_xor(mx, 16));
            mx = fmaxf(mx, __shfl_xor(mx, 32));
            if (__any(mx > m_s + 8.0f)) {  // defer-max
                const float mnew = fmaxf(m_s, mx);
                const float fac = __builtin_amdgcn_exp2f(m_s - mnew);
                m_s = mnew;
                l_s *= fac;
#pragma unroll
                for (int r = 0; r < 4; ++r) {
                    const float fr = __shfl(fac, (l4 << 4) | (l4 * 4 + r));
#pragma unroll
                    for (int ni = 0; ni < 4; ++ni) o[ni][r] *= fr;
                }
            }
            float rs = 0.f;
            unsigned pw[8];
#pragma unroll
            for (int i = 0; i < 4; ++i) {
                float pv[4];
#pragma unroll
                for (int r = 0; r < 4; ++r) {
                    pv[r] = __builtin_amdgcn_exp2f(tv[i][r] - m_s);
                    rs += pv[r];
                }
                pw[i * 2 + 0] = cvt_pk(pv[0], pv[1]);
                pw[i * 2 + 1] = cvt_pk(pv[2], pv[3]);
            }
            rs += __shfl_xor(rs, 16);
            rs += __shfl_xor(rs, 32);
            l_s += rs;
            __builtin_amdgcn_s_setprio(1);
#pragma unroll
            for (int st = 0; st < 2; ++st) {
                const u32x4 pk = {pw[st * 4 + 0], pw[st * 4 + 1], pw[st * 4 + 2],
                                  pw[st * 4 + 3]};
                const bf16x8 pf = __builtin_bit_cast(bf16x8, pk);
#pragma unroll
                for (int ni = 0; ni < 4; ++ni) {
                    const unsigned short* vb =
                        Vb + (l4 * 4 + st * 2) * 256 + (ni * 16 + l15) * 4;
                    const u32x2 va = *(const u32x2*)vb;
                    const u32x2 vc = *(const u32x2*)(vb + 256);
                    const u32x4 vv = {va.x, va.y, vc.x, vc.y};
                    const bf16x8 vf = __builtin_bit_cast(bf16x8, vv);
                    o[ni] = MFMA16(pf, vf, o[ni]);
                }
            }
            __builtin_amdgcn_s_setprio(0);
        };

        __syncthreads();
        STAGE(0, 0);
        __syncthreads();
        for (int kt = 0; kt < qt; ++kt) {
            STAGE(kt + 1, (kt + 1) & 1);
            COMPUTE(kt & 1, false);
            __syncthreads();
        }
        COMPUTE(qt & 1, true);

        unsigned short* aop = ao + (size_t)(b * T_ + qt * 64 + w * 16) * 1024 + h * 64;
#pragma unroll
        for (int r = 0; r < 4; ++r) {
            const float lr = __shfl(l_s, (l4 << 4) | (l4 * 4 + r));
            const float inv = 1.0f / lr;
#pragma unroll
            for (int ni = 0; ni < 4; ++ni)
                aop[(size_t)(l4 * 4 + r) * 1024 + ni * 16 + l15] = f2b(o[ni][r] * inv);
        }
    }
}

extern "C" void kernel_launch(void* const* d_in, const int* in_sizes, int n_in,
                              void* d_out, int out_size, void* d_ws, size_t ws_size,
                              hipStream_t stream) {
    (void)in_sizes; (void)n_in; (void)out_size; (void)ws_size;
    const float* x = (const float*)d_in[0];
    const float* Wqkv = (const float*)d_in[1];
    const float* Wout = (const float*)d_in[2];
    char* ws = (char*)d_ws;
    unsigned short* xb = (unsigned short*)(ws + 0);             // 16 MB
    unsigned short* wqkvT = (unsigned short*)(ws + 16777216);   // 6 MB  (3072 x 1024)
    unsigned short* woutT = (unsigned short*)(ws + 23068672);   // 2 MB  (1024 x 1024)
    unsigned short* qkvb = (unsigned short*)(ws + 25165824);    // 48 MB (8192 x 3072, V third unused)
    unsigned short* vt2 = (unsigned short*)(ws + 75497472);     // 16 MB (64 x 512 x 64 x 4)
    unsigned short* ao = (unsigned short*)(ws + 92274688);      // 16 MB (8192 x 1024)

    k_cvt<<<2048, 256, 0, stream>>>(x, xb, 4 * T_ * 1024);
    k_cvt_T<1024, 3072><<<16 * 48, 256, 0, stream>>>(Wqkv, wqkvT);
    k_cvt_T<1024, 1024><<<16 * 16, 256, 0, stream>>>(Wout, woutT);
    k_gemm256<0, 3072><<<dim3(24, 32), 512, 0, stream>>>(xb, wqkvT, qkvb, vt2);
    k_attn<<<1024, 256, 0, stream>>>(qkvb, vt2, ao);
    k_gemm256<1, 1024><<<dim3(8, 32), 512, 0, stream>>>(ao, woutT, d_out, nullptr);
}